// Round 3
// baseline (40.792 us; speedup 1.0000x reference)
//
#include <hip/hip_runtime.h>

// WOMD post-processing v3: one wave = two agents (lanes 0-31 / 32-63).
// ALL private state is scalar-per-lane or statically-indexed (no scratch).
// MPA tail is lane-parallel (lanes 0-5 of each 32-group own one pick each);
// argsort -> rank via shuffles, sequential scan via ballot+shuffle.

#define NSC 64
#define NAG 64
#define NJF 32
#define NSTEP 80
#define KP 6
#define TOUT 16

struct F3 { float x, y, z; };

__global__ __launch_bounds__(64)
void womd_pp3(const float* __restrict__ ag_type,
              const float* __restrict__ trajs,
              const float* __restrict__ scores,
              float* __restrict__ out)
{
    const int tid  = threadIdx.x;
    const int half = tid >> 5;          // which agent of the pair
    const int hl   = tid & 31;          // lane within 32-group = mode index
    const int s    = blockIdx.x >> 5;   // scene
    const int p    = blockIdx.x & 31;   // agent-pair
    const int a    = p * 2 + half;      // agent

    __shared__ float exs[2][NJF][2];    // endpoint broadcast

    // ---- loads ----
    float raw = scores[((size_t)s * NJF + hl) * NAG + a];
    size_t eoff = (((size_t)(s * NJF + hl) * NAG + a) * NSTEP + (NSTEP - 1)) * 3;
    float exx = trajs[eoff];
    float exy = trajs[eoff + 1];
    const float* at = ag_type + (size_t)(s * NAG + a) * 3;
    const float thresh = at[0] * 2.5f + at[1] * 1.0f + at[2] * 2.0f;

    exs[half][hl][0] = exx;
    exs[half][hl][1] = exy;

    // ---- softmax over 32 modes (butterfly, 1 expf/lane) ----
    float mx = raw;
    #pragma unroll
    for (int off = 16; off > 0; off >>= 1)
        mx = fmaxf(mx, __shfl_xor(mx, off, 32));
    float ev = expf(raw - mx);
    float sum = ev;
    #pragma unroll
    for (int off = 16; off > 0; off >>= 1)
        sum += __shfl_xor(sum, off, 32);
    float sm = ev / sum;

    __syncthreads();

    // ---- within bitmask row (strict <, sqrt) ----
    unsigned m = 0;
    #pragma unroll
    for (int j = 0; j < NJF; ++j) {
        float dx = exx - exs[half][j][0];
        float dy = exy - exs[half][j][1];
        m |= (sqrtf(dx * dx + dy * dy) < thresh) ? (1u << j) : 0u;
    }

    // ---- MTR NMS: 6 picks, butterfly argmax (first-index tie-break) ----
    int sel[KP];                        // written/read with literal indices only
    float ls = sm;
    #pragma unroll
    for (int k = 0; k < KP; ++k) {
        float v = ls; int idx = hl;
        #pragma unroll
        for (int off = 16; off > 0; off >>= 1) {
            float ov = __shfl_xor(v, off, 32);
            int   oi = __shfl_xor(idx, off, 32);
            bool take = (ov > v) || (ov == v && oi < idx);
            v   = take ? ov : v;
            idx = take ? oi : idx;
        }
        sel[k] = idx;                   // k is a literal after unroll
        unsigned wb = __shfl(m, idx, 32);
        ls *= ((wb >> hl) & 1u) ? 0.01f : 1.0f;
        ls = (hl == idx) ? -1.0f : ls;
    }

    // ---- trajectory gather: issue loads NOW (overlap the MPA tail) ----
    F3 pt[3];
    #pragma unroll
    for (int i = 0; i < 3; ++i) {
        int mode = (hl < 16) ? sel[2 * i] : sel[2 * i + 1];   // static sel idx
        int t = hl & 15;
        size_t src = (((size_t)(s * NJF + mode) * NAG + a) * NSTEP + (4 + 5 * t)) * 3;
        pt[i] = *(const F3*)(trajs + src);
    }

    // ---- MPA tail, lane-parallel on lanes 0-5 of each 32-group ----
    const bool active = (hl < KP);
    // my pick (static select chain)
    int mySel = sel[0];
    mySel = (hl == 1) ? sel[1] : mySel;
    mySel = (hl == 2) ? sel[2] : mySel;
    mySel = (hl == 3) ? sel[3] : mySel;
    mySel = (hl == 4) ? sel[4] : mySel;
    mySel = (hl == 5) ? sel[5] : mySel;

    float mySk = __shfl(sm, mySel, 32);
    float myX  = __shfl(exx, mySel, 32);
    float myY  = __shfl(exy, mySel, 32);

    // normalize selected scores
    float t0 = active ? mySk : 0.f;
    t0 += __shfl_xor(t0, 4, 8);
    t0 += __shfl_xor(t0, 2, 8);
    t0 += __shfl_xor(t0, 1, 8);
    float skn = mySk / t0;

    // 6x6 within row + stable descending rank
    unsigned w2row = 0;
    int rank = 0;
    #pragma unroll
    for (int jj = 0; jj < KP; ++jj) {
        float ox  = __shfl(myX, jj, 32);
        float oy  = __shfl(myY, jj, 32);
        float osk = __shfl(skn, jj, 32);
        float dx = myX - ox, dy = myY - oy;
        if (sqrtf(dx * dx + dy * dy) < thresh) w2row |= (1u << jj);
        rank += ((osk > skn) || (osk == skn && jj < hl)) ? 1 : 0;
    }
    if (!active) rank = 99;

    // sequential MPA scan in rank order (ballot to find the rank-t lane)
    #pragma unroll
    for (int t = 0; t < KP; ++t) {
        unsigned long long bal = __ballot(rank == t);
        unsigned bits = half ? (unsigned)(bal >> 32) : (unsigned)bal;
        int kk = __ffs(bits) - 1;                 // lane (0..5) holding rank t
        float sk_k = __shfl(skn, kk, 32);
        bool cond = active && ((w2row >> kk) & 1u) && (skn > sk_k);
        unsigned long long b2 = __ballot(cond);
        unsigned hb = half ? (unsigned)(b2 >> 32) : (unsigned)b2;
        if (hb != 0 && hl == kk) skn = 0.001f;
    }

    // normalize; softmax(log p / 0.5) == p^2 / sum(p^2)
    float t1 = active ? skn : 0.f;
    t1 += __shfl_xor(t1, 4, 8);
    t1 += __shfl_xor(t1, 2, 8);
    t1 += __shfl_xor(t1, 1, 8);
    float pn = skn / t1;
    float q = pn * pn;
    float t2 = active ? q : 0.f;
    t2 += __shfl_xor(t2, 4, 8);
    t2 += __shfl_xor(t2, 2, 8);
    t2 += __shfl_xor(t2, 1, 8);

    const size_t SCBASE = (size_t)NSC * NAG * KP * TOUT * 3;
    if (active) out[SCBASE + ((size_t)s * NAG + a) * KP + hl] = q / t2;

    // ---- trajectory stores (loads were in flight during the tail) ----
    size_t ob = ((size_t)s * NAG + a) * (KP * TOUT * 3);
    #pragma unroll
    for (int i = 0; i < 3; ++i) {
        *(F3*)(out + ob + (size_t)(hl + 32 * i) * 3) = pt[i];
    }
}

extern "C" void kernel_launch(void* const* d_in, const int* in_sizes, int n_in,
                              void* d_out, int out_size, void* d_ws, size_t ws_size,
                              hipStream_t stream) {
    const float* ag_type = (const float*)d_in[0];
    const float* trajs   = (const float*)d_in[1];
    const float* scores  = (const float*)d_in[2];
    float* out = (float*)d_out;

    womd_pp3<<<NSC * (NAG / 2), 64, 0, stream>>>(ag_type, trajs, scores, out);
}